// Round 2
// baseline (304.320 us; speedup 1.0000x reference)
//
#include <hip/hip_runtime.h>
#include <cstdint>
#include <cstddef>

#define B_ 64
#define T_ 800
#define J_ 50
#define D_ 200
#define TILE1 50      // t-rows per k1 block
#define NTILE1 16     // T_/TILE1
#define TT 5          // t-rows per wave pass
#define NPASS 10      // TILE1/TT

__device__ __forceinline__ float dot4(float4 a, float4 b) {
    return fmaf(a.x, b.x, fmaf(a.y, b.y, fmaf(a.z, b.z, a.w * b.w)));
}
__device__ __forceinline__ float rlane(float v, int l) {
    return __int_as_float(__builtin_amdgcn_readlane(__float_as_int(v), l));
}

// ---------------- K1: s, softmax_j, c2q, g chunks 0/1/2, smax; zero q2c ----------------
// LDS = exactly 40,000B (u*w_hu tile, rotation-swizzled) -> 4 blocks/CU.
__global__ __launch_bounds__(256, 4) void k1_kernel(
    const float* __restrict__ h, const float* __restrict__ u,
    const float* __restrict__ w_h, const float* __restrict__ b_h,
    const float* __restrict__ w_u, const float* __restrict__ b_u,
    const float* __restrict__ w_hu, const float* __restrict__ b_hu,
    float* __restrict__ g, float* __restrict__ smax_ws, float* __restrict__ q2c)
{
    __shared__ __align__(16) float4 uh_s[50][50];   // uh_s[j][rot(k,j)] = u[j][k4]*w_hu[k4]

    const int tid  = threadIdx.x;
    const int b    = blockIdx.x >> 4;
    const int tile = blockIdx.x & 15;

    // zero q2c (ws is re-poisoned every launch); k3 accumulates atomically later
    if (tile == 0 && tid < D_) q2c[b * D_ + tid] = 0.f;

    // ---- stage uh = u * w_hu with rotation swizzle: col kk = (k + ((j>>2)&7)) mod 50 ----
    for (int idx = tid; idx < 2500; idx += 256) {
        const int j = idx / 50, k = idx - (idx / 50) * 50;
        const float4 uu = *reinterpret_cast<const float4*>(&u[(b * J_ + j) * D_ + 4 * k]);
        const float4 ww = *reinterpret_cast<const float4*>(&w_hu[4 * k]);
        float4 p; p.x = uu.x * ww.x; p.y = uu.y * ww.y; p.z = uu.z * ww.z; p.w = uu.w * ww.w;
        int kk = k + ((j >> 2) & 7); if (kk >= 50) kk -= 50;
        uh_s[j][kk] = p;
    }

    const int lane = tid & 63;
    const int wfl  = __builtin_amdgcn_readfirstlane(tid >> 6);   // force SGPR wave id

    // per-lane w_h fragment (lane = d4 chunk)
    float4 wh_r = make_float4(0.f, 0.f, 0.f, 0.f);
    if (lane < 50) wh_r = *reinterpret_cast<const float4*>(&w_h[4 * lane]);

    // ---- su[lane] = dot(u_row_lane, w_u) + biases (lane = j); w_u via scalar loads ----
    float su = b_h[0] + b_u[0] + b_hu[0];
    {
        const int j = (lane < J_) ? lane : 0;
        const float* ur = u + (size_t)(b * J_ + j) * D_;
        #pragma unroll 5
        for (int k = 0; k < 50; ++k) {
            const float4 uu = *reinterpret_cast<const float4*>(&ur[4 * k]);
            su = fmaf(uu.x, w_u[4 * k + 0], su);
            su = fmaf(uu.y, w_u[4 * k + 1], su);
            su = fmaf(uu.z, w_u[4 * k + 2], su);
            su = fmaf(uu.w, w_u[4 * k + 3], su);
        }
    }
    __syncthreads();

    const int urow = (lane < 50) ? lane : 49;
    const int crot = (urow >> 2) & 7;
    const int dcol = (lane < 50) ? lane : 0;

    for (int p = wfl; p < NPASS; p += 4) {
        const int t0 = tile * TILE1 + p * TT;

        // ---- Phase A: load h rows (lane=d4), sh allreduce ----
        float4 h4r[TT];
        float  shr[TT];
        const float* hrow[TT];
        #pragma unroll
        for (int tt = 0; tt < TT; ++tt) {
            const int t = t0 + tt;
            hrow[tt] = h + (size_t)(b * T_ + t) * D_;   // uniform pointer
            float4 h4 = make_float4(0.f, 0.f, 0.f, 0.f);
            if (lane < 50) h4 = *reinterpret_cast<const float4*>(&hrow[tt][4 * lane]);
            h4r[tt] = h4;
            float ps = dot4(h4, wh_r);
            #pragma unroll
            for (int off = 32; off > 0; off >>= 1) ps += __shfl_xor(ps, off);
            shr[tt] = ps;
        }

        // ---- Phase B: s[tt](lane=j) = su + sh + sum_k dot(uh[j][k], h[t][k4]) ----
        // h[t][*] read through uniform pointers -> scalar loads (SMEM pipe).
        float s[TT];
        #pragma unroll
        for (int tt = 0; tt < TT; ++tt) s[tt] = su + shr[tt];
        #pragma unroll 5
        for (int k = 0; k < 50; ++k) {
            int kk = k + crot; if (kk >= 50) kk -= 50;
            const float4 uh = uh_s[urow][kk];
            #pragma unroll
            for (int tt = 0; tt < TT; ++tt) {
                const float* hr = hrow[tt];
                float acc = s[tt];
                acc = fmaf(uh.x, hr[4 * k + 0], acc);
                acc = fmaf(uh.y, hr[4 * k + 1], acc);
                acc = fmaf(uh.z, hr[4 * k + 2], acc);
                acc = fmaf(uh.w, hr[4 * k + 3], acc);
                s[tt] = acc;
            }
        }

        // ---- Phase C: softmax over j-lanes (register), write smax ----
        float a[TT];
        #pragma unroll
        for (int tt = 0; tt < TT; ++tt) {
            float m = (lane < J_) ? s[tt] : -3.4e38f;
            #pragma unroll
            for (int off = 32; off > 0; off >>= 1) m = fmaxf(m, __shfl_xor(m, off));
            float e = (lane < J_) ? __expf(s[tt] - m) : 0.f;
            float sum = e;
            #pragma unroll
            for (int off = 32; off > 0; off >>= 1) sum += __shfl_xor(sum, off);
            a[tt] = e / sum;
            if (lane == 0) smax_ws[b * T_ + (t0 + tt)] = m;
        }

        // ---- Phase D: c2q[tt][d4] = sum_j a[j] * u[j][d4]; u cols from global (L2-hot),
        //      a broadcast via v_readlane ----
        float4 c2q[TT];
        #pragma unroll
        for (int tt = 0; tt < TT; ++tt) c2q[tt] = make_float4(0.f, 0.f, 0.f, 0.f);
        const float* ub = u + (size_t)b * J_ * D_;
        #pragma unroll 2
        for (int j = 0; j < J_; ++j) {
            const float4 uc = *reinterpret_cast<const float4*>(&ub[(size_t)j * D_ + 4 * dcol]);
            #pragma unroll
            for (int tt = 0; tt < TT; ++tt) {
                const float ab = rlane(a[tt], j);
                c2q[tt].x = fmaf(ab, uc.x, c2q[tt].x);
                c2q[tt].y = fmaf(ab, uc.y, c2q[tt].y);
                c2q[tt].z = fmaf(ab, uc.z, c2q[tt].z);
                c2q[tt].w = fmaf(ab, uc.w, c2q[tt].w);
            }
        }

        // ---- Epilogue: g chunks 0 (h), 1 (c2q), 2 (h*c2q) ----
        #pragma unroll
        for (int tt = 0; tt < TT; ++tt) {
            const int t = t0 + tt;
            if (lane < 50) {
                const size_t go = (size_t)(b * T_ + t) * (4 * D_) + 4 * lane;
                *reinterpret_cast<float4*>(&g[go]) = h4r[tt];
                *reinterpret_cast<float4*>(&g[go + D_]) = c2q[tt];
                float4 hc;
                hc.x = h4r[tt].x * c2q[tt].x; hc.y = h4r[tt].y * c2q[tt].y;
                hc.z = h4r[tt].z * c2q[tt].z; hc.w = h4r[tt].w * c2q[tt].w;
                *reinterpret_cast<float4*>(&g[go + 2 * D_]) = hc;
            }
        }
    }
}

// ---------------- K3: softmax over t (recomputed per block) + partial q2c ----------------
__global__ __launch_bounds__(256) void k3_kernel(const float* __restrict__ h,
                                                 const float* __restrict__ smax,
                                                 float* __restrict__ q2c)
{
    const int b = blockIdx.x >> 3, t8 = blockIdx.x & 7;
    const int rows0 = t8 * 100;
    const int tid = threadIdx.x, lane = tid & 63, w = tid >> 6;
    __shared__ float red[4];
    __shared__ float bs[100];

    // global max over T
    float v[4];
    float m = -3.4e38f;
    #pragma unroll
    for (int k = 0; k < 4; ++k) {
        const int t = tid + 256 * k;
        v[k] = (t < T_) ? smax[b * T_ + t] : -3.4e38f;
        m = fmaxf(m, v[k]);
    }
    #pragma unroll
    for (int off = 32; off > 0; off >>= 1) m = fmaxf(m, __shfl_xor(m, off));
    if (lane == 0) red[w] = m;
    __syncthreads();
    m = fmaxf(fmaxf(red[0], red[1]), fmaxf(red[2], red[3]));
    __syncthreads();

    // global sum of exp
    float sum = 0.f;
    #pragma unroll
    for (int k = 0; k < 4; ++k) {
        const int t = tid + 256 * k;
        sum += (t < T_) ? __expf(v[k] - m) : 0.f;
    }
    #pragma unroll
    for (int off = 32; off > 0; off >>= 1) sum += __shfl_xor(sum, off);
    if (lane == 0) red[w] = sum;
    __syncthreads();
    sum = red[0] + red[1] + red[2] + red[3];
    const float inv = 1.f / sum;

    if (tid < 100) bs[tid] = __expf(smax[b * T_ + rows0 + tid] - m) * inv;
    __syncthreads();

    if (tid < D_) {
        const float* hp = h + ((size_t)b * T_ + rows0) * D_ + tid;
        float acc = 0.f;
        #pragma unroll 10
        for (int i = 0; i < 100; ++i) acc = fmaf(bs[i], hp[(size_t)i * D_], acc);
        atomicAdd(&q2c[b * D_ + tid], acc);
    }
}

// ---------------- K4: g chunk 3 = h * q2c ----------------
__global__ __launch_bounds__(256) void k4_kernel(const float* __restrict__ h,
                                                 const float* __restrict__ q2c,
                                                 float* __restrict__ g)
{
    const int b = blockIdx.x >> 4, tc = blockIdx.x & 15;
    const int tid = threadIdx.x;
    if (tid >= 250) return;
    const int tl = tid / 50, d4 = tid - tl * 50;
    const float4 q = *reinterpret_cast<const float4*>(&q2c[b * D_ + 4 * d4]);
    const int trow0 = tc * 50 + tl;
    #pragma unroll 5
    for (int i = 0; i < 10; ++i) {
        const int t = trow0 + 5 * i;
        const float4 h4 = *reinterpret_cast<const float4*>(&h[(size_t)(b * T_ + t) * D_ + 4 * d4]);
        float4 o;
        o.x = h4.x * q.x; o.y = h4.y * q.y; o.z = h4.z * q.z; o.w = h4.w * q.w;
        *reinterpret_cast<float4*>(&g[(size_t)(b * T_ + t) * (4 * D_) + 3 * D_ + 4 * d4]) = o;
    }
}

extern "C" void kernel_launch(void* const* d_in, const int* in_sizes, int n_in,
                              void* d_out, int out_size, void* d_ws, size_t ws_size,
                              hipStream_t stream)
{
    const float* h    = (const float*)d_in[0];
    const float* u    = (const float*)d_in[1];
    const float* w_h  = (const float*)d_in[2];
    const float* b_h  = (const float*)d_in[3];
    const float* w_u  = (const float*)d_in[4];
    const float* b_u  = (const float*)d_in[5];
    const float* w_hu = (const float*)d_in[6];
    const float* b_hu = (const float*)d_in[7];
    float* g = (float*)d_out;

    float* smax = (float*)d_ws;          // B*T floats
    float* q2c  = smax + B_ * T_;        // B*D floats

    k1_kernel<<<dim3(B_ * NTILE1), dim3(256), 0, stream>>>(h, u, w_h, b_h, w_u, b_u, w_hu, b_hu, g, smax, q2c);
    k3_kernel<<<dim3(B_ * 8), dim3(256), 0, stream>>>(h, smax, q2c);
    k4_kernel<<<dim3(B_ * NTILE1), dim3(256), 0, stream>>>(h, q2c, g);
}

// Round 4
// 276.784 us; speedup vs baseline: 1.0995x; 1.0995x over previous
//
#include <hip/hip_runtime.h>
#include <cstdint>
#include <cstddef>

#define B_ 64
#define T_ 800
#define J_ 50
#define D_ 200
#define TILE1 100     // t-rows per k1 block
#define NTILE1 8      // T_/TILE1
#define NW 8          // waves per k1 block (512 threads)
#define TT 5          // t-rows per wave pass
#define NPASS 20      // TILE1/TT

__device__ __forceinline__ float dot4(float4 a, float4 b) {
    return fmaf(a.x, b.x, fmaf(a.y, b.y, fmaf(a.z, b.z, a.w * b.w)));
}
__device__ __forceinline__ int rotc(int k, int j) {   // rotation swizzle column
    int kk = k + ((j >> 2) & 7);
    return (kk >= 50) ? kk - 50 : kk;
}

// ---- K1: s, softmax_j, c2q, g chunks 0/1/2, smax; zero q2c ----
// LDS 64,528 B -> 2 blocks/CU, 16 waves/CU.
__global__ __launch_bounds__(512, 4) void k1_kernel(
    const float* __restrict__ h, const float* __restrict__ u,
    const float* __restrict__ w_h, const float* __restrict__ b_h,
    const float* __restrict__ w_u, const float* __restrict__ b_u,
    const float* __restrict__ w_hu, const float* __restrict__ b_hu,
    float* __restrict__ g, float* __restrict__ smax_ws, float* __restrict__ q2c)
{
    __shared__ __align__(16) float4 u4_s[50][50];       // raw u, rot-swizzled (40000 B)
    __shared__ __align__(16) float4 hw_s[NW][TT][25];   // hw d-half stage (16000 B)
    __shared__ float a_s[NW][TT][52];                   // attention rows (8320 B)

    const int tid  = threadIdx.x;
    const int b    = blockIdx.x >> 3;
    const int tile = blockIdx.x & 7;

    if (tile == 0 && tid < D_) q2c[b * D_ + tid] = 0.f;   // ws is re-poisoned each launch

    // ---- stage raw u with rotation swizzle ----
    for (int idx = tid; idx < 2500; idx += 512) {
        const int j = idx / 50, k = idx - (idx / 50) * 50;
        u4_s[j][rotc(k, j)] = *reinterpret_cast<const float4*>(&u[(b * J_ + j) * D_ + 4 * k]);
    }
    __syncthreads();

    const int lane = tid & 63;
    const int w    = tid >> 6;
    const int urow = (lane < 50) ? lane : 49;
    const int dcol = (lane < 50) ? lane : 0;

    float4 whu_r = make_float4(0.f, 0.f, 0.f, 0.f);
    float4 wh_r  = make_float4(0.f, 0.f, 0.f, 0.f);
    if (lane < 50) {
        whu_r = *reinterpret_cast<const float4*>(&w_hu[4 * lane]);
        wh_r  = *reinterpret_cast<const float4*>(&w_h[4 * lane]);
    }

    // ---- su[lane=j] = dot(u_j, w_u) + biases, from LDS u + uniform w_u ----
    float su = b_h[0] + b_u[0] + b_hu[0];
    #pragma unroll 5
    for (int k = 0; k < 50; ++k) {
        const float4 wu4 = *reinterpret_cast<const float4*>(&w_u[4 * k]);  // uniform
        su += dot4(u4_s[urow][rotc(k, urow)], wu4);
    }

    for (int p = w; p < NPASS; p += NW) {
        const int t0 = tile * TILE1 + p * TT;

        // ---- Phase A: load h rows (lane=d4), write hw half0, sh allreduce ----
        float4 h4r[TT];
        float  shr[TT];
        #pragma unroll
        for (int tt = 0; tt < TT; ++tt) {
            float4 h4 = make_float4(0.f, 0.f, 0.f, 0.f);
            if (lane < 50)
                h4 = *reinterpret_cast<const float4*>(&h[(size_t)(b * T_ + t0 + tt) * D_ + 4 * lane]);
            h4r[tt] = h4;
            if (lane < 25) {   // hw half 0 (d4 = 0..24)
                float4 hw; hw.x = h4.x * whu_r.x; hw.y = h4.y * whu_r.y;
                hw.z = h4.z * whu_r.z; hw.w = h4.w * whu_r.w;
                hw_s[w][tt][lane] = hw;
            }
            float ps = dot4(h4, wh_r);
            #pragma unroll
            for (int off = 32; off > 0; off >>= 1) ps += __shfl_xor(ps, off);
            shr[tt] = ps;
        }

        // ---- Phase B: s[tt](lane=j) = su + sh + sum_k dot(hw[t][k], u[j][k]) ----
        float s[TT];
        #pragma unroll
        for (int tt = 0; tt < TT; ++tt) s[tt] = su + shr[tt];

        #pragma unroll 5
        for (int k = 0; k < 25; ++k) {           // half 0
            const float4 u4 = u4_s[urow][rotc(k, urow)];
            #pragma unroll
            for (int tt = 0; tt < TT; ++tt) s[tt] += dot4(hw_s[w][tt][k], u4);
        }
        #pragma unroll
        for (int tt = 0; tt < TT; ++tt) {        // stage hw half 1 (d4 = 25..49)
            if (lane >= 25 && lane < 50) {
                float4 hw; hw.x = h4r[tt].x * whu_r.x; hw.y = h4r[tt].y * whu_r.y;
                hw.z = h4r[tt].z * whu_r.z; hw.w = h4r[tt].w * whu_r.w;
                hw_s[w][tt][lane - 25] = hw;
            }
        }
        #pragma unroll 5
        for (int k = 25; k < 50; ++k) {          // half 1
            const float4 u4 = u4_s[urow][rotc(k, urow)];
            #pragma unroll
            for (int tt = 0; tt < TT; ++tt) s[tt] += dot4(hw_s[w][tt][k - 25], u4);
        }

        // ---- Phase C: softmax over j-lanes; a -> LDS; smax -> ws ----
        #pragma unroll
        for (int tt = 0; tt < TT; ++tt) {
            float m = (lane < J_) ? s[tt] : -3.4e38f;
            #pragma unroll
            for (int off = 32; off > 0; off >>= 1) m = fmaxf(m, __shfl_xor(m, off));
            float e = (lane < J_) ? __expf(s[tt] - m) : 0.f;
            float sum = e;
            #pragma unroll
            for (int off = 32; off > 0; off >>= 1) sum += __shfl_xor(sum, off);
            if (lane < J_) a_s[w][tt][lane] = e / sum;
            if (lane == 0) smax_ws[b * T_ + (t0 + tt)] = m;
        }

        // ---- Phase D: c2q[tt][d4=lane] = sum_j a[j] * u[j][d4], all from LDS ----
        float4 c2q[TT];
        #pragma unroll
        for (int tt = 0; tt < TT; ++tt) c2q[tt] = make_float4(0.f, 0.f, 0.f, 0.f);
        #pragma unroll 3
        for (int j4 = 0; j4 < 12; ++j4) {
            const float4 ua0 = u4_s[4 * j4 + 0][rotc(dcol, 4 * j4 + 0)];
            const float4 ua1 = u4_s[4 * j4 + 1][rotc(dcol, 4 * j4 + 1)];
            const float4 ua2 = u4_s[4 * j4 + 2][rotc(dcol, 4 * j4 + 2)];
            const float4 ua3 = u4_s[4 * j4 + 3][rotc(dcol, 4 * j4 + 3)];
            #pragma unroll
            for (int tt = 0; tt < TT; ++tt) {
                const float4 a4 = *reinterpret_cast<const float4*>(&a_s[w][tt][4 * j4]);
                c2q[tt].x = fmaf(a4.x, ua0.x, c2q[tt].x);
                c2q[tt].y = fmaf(a4.x, ua0.y, c2q[tt].y);
                c2q[tt].z = fmaf(a4.x, ua0.z, c2q[tt].z);
                c2q[tt].w = fmaf(a4.x, ua0.w, c2q[tt].w);
                c2q[tt].x = fmaf(a4.y, ua1.x, c2q[tt].x);
                c2q[tt].y = fmaf(a4.y, ua1.y, c2q[tt].y);
                c2q[tt].z = fmaf(a4.y, ua1.z, c2q[tt].z);
                c2q[tt].w = fmaf(a4.y, ua1.w, c2q[tt].w);
                c2q[tt].x = fmaf(a4.z, ua2.x, c2q[tt].x);
                c2q[tt].y = fmaf(a4.z, ua2.y, c2q[tt].y);
                c2q[tt].z = fmaf(a4.z, ua2.z, c2q[tt].z);
                c2q[tt].w = fmaf(a4.z, ua2.w, c2q[tt].w);
                c2q[tt].x = fmaf(a4.w, ua3.x, c2q[tt].x);
                c2q[tt].y = fmaf(a4.w, ua3.y, c2q[tt].y);
                c2q[tt].z = fmaf(a4.w, ua3.z, c2q[tt].z);
                c2q[tt].w = fmaf(a4.w, ua3.w, c2q[tt].w);
            }
        }
        {   // tail j = 48, 49
            const float4 ua0 = u4_s[48][rotc(dcol, 48)];
            const float4 ua1 = u4_s[49][rotc(dcol, 49)];
            #pragma unroll
            for (int tt = 0; tt < TT; ++tt) {
                const float a0 = a_s[w][tt][48], a1 = a_s[w][tt][49];
                c2q[tt].x = fmaf(a0, ua0.x, c2q[tt].x);
                c2q[tt].y = fmaf(a0, ua0.y, c2q[tt].y);
                c2q[tt].z = fmaf(a0, ua0.z, c2q[tt].z);
                c2q[tt].w = fmaf(a0, ua0.w, c2q[tt].w);
                c2q[tt].x = fmaf(a1, ua1.x, c2q[tt].x);
                c2q[tt].y = fmaf(a1, ua1.y, c2q[tt].y);
                c2q[tt].z = fmaf(a1, ua1.z, c2q[tt].z);
                c2q[tt].w = fmaf(a1, ua1.w, c2q[tt].w);
            }
        }

        // ---- Epilogue: g chunks 0 (h), 1 (c2q), 2 (h*c2q) ----
        #pragma unroll
        for (int tt = 0; tt < TT; ++tt) {
            if (lane < 50) {
                const size_t go = (size_t)(b * T_ + t0 + tt) * (4 * D_) + 4 * lane;
                *reinterpret_cast<float4*>(&g[go]) = h4r[tt];
                *reinterpret_cast<float4*>(&g[go + D_]) = c2q[tt];
                float4 hc;
                hc.x = h4r[tt].x * c2q[tt].x; hc.y = h4r[tt].y * c2q[tt].y;
                hc.z = h4r[tt].z * c2q[tt].z; hc.w = h4r[tt].w * c2q[tt].w;
                *reinterpret_cast<float4*>(&g[go + 2 * D_]) = hc;
            }
        }
    }
}

// ---- K3: softmax over t (recomputed per block) + partial q2c ----
__global__ __launch_bounds__(256) void k3_kernel(const float* __restrict__ h,
                                                 const float* __restrict__ smax,
                                                 float* __restrict__ q2c)
{
    const int b = blockIdx.x >> 3, t8 = blockIdx.x & 7;
    const int rows0 = t8 * 100;
    const int tid = threadIdx.x, lane = tid & 63, w = tid >> 6;
    __shared__ float red[4];
    __shared__ float bs[100];

    float v[4];
    float m = -3.4e38f;
    #pragma unroll
    for (int k = 0; k < 4; ++k) {
        const int t = tid + 256 * k;
        v[k] = (t < T_) ? smax[b * T_ + t] : -3.4e38f;
        m = fmaxf(m, v[k]);
    }
    #pragma unroll
    for (int off = 32; off > 0; off >>= 1) m = fmaxf(m, __shfl_xor(m, off));
    if (lane == 0) red[w] = m;
    __syncthreads();
    m = fmaxf(fmaxf(red[0], red[1]), fmaxf(red[2], red[3]));
    __syncthreads();

    float sum = 0.f;
    #pragma unroll
    for (int k = 0; k < 4; ++k) {
        const int t = tid + 256 * k;
        sum += (t < T_) ? __expf(v[k] - m) : 0.f;
    }
    #pragma unroll
    for (int off = 32; off > 0; off >>= 1) sum += __shfl_xor(sum, off);
    if (lane == 0) red[w] = sum;
    __syncthreads();
    sum = red[0] + red[1] + red[2] + red[3];
    const float inv = 1.f / sum;

    if (tid < 100) bs[tid] = __expf(smax[b * T_ + rows0 + tid] - m) * inv;
    __syncthreads();

    if (tid < D_) {
        const float* hp = h + ((size_t)b * T_ + rows0) * D_ + tid;
        float acc = 0.f;
        #pragma unroll 10
        for (int i = 0; i < 100; ++i) acc = fmaf(bs[i], hp[(size_t)i * D_], acc);
        atomicAdd(&q2c[b * D_ + tid], acc);
    }
}

// ---- K4: g chunk 3 = h * q2c ----
__global__ __launch_bounds__(256) void k4_kernel(const float* __restrict__ h,
                                                 const float* __restrict__ q2c,
                                                 float* __restrict__ g)
{
    const int b = blockIdx.x >> 4, tc = blockIdx.x & 15;
    const int tid = threadIdx.x;
    if (tid >= 250) return;
    const int tl = tid / 50, d4 = tid - tl * 50;
    const float4 q = *reinterpret_cast<const float4*>(&q2c[b * D_ + 4 * d4]);
    const int trow0 = tc * 50 + tl;
    #pragma unroll 5
    for (int i = 0; i < 10; ++i) {
        const int t = trow0 + 5 * i;
        const float4 h4 = *reinterpret_cast<const float4*>(&h[(size_t)(b * T_ + t) * D_ + 4 * d4]);
        float4 o;
        o.x = h4.x * q.x; o.y = h4.y * q.y; o.z = h4.z * q.z; o.w = h4.w * q.w;
        *reinterpret_cast<float4*>(&g[(size_t)(b * T_ + t) * (4 * D_) + 3 * D_ + 4 * d4]) = o;
    }
}

extern "C" void kernel_launch(void* const* d_in, const int* in_sizes, int n_in,
                              void* d_out, int out_size, void* d_ws, size_t ws_size,
                              hipStream_t stream)
{
    const float* h    = (const float*)d_in[0];
    const float* u    = (const float*)d_in[1];
    const float* w_h  = (const float*)d_in[2];
    const float* b_h  = (const float*)d_in[3];
    const float* w_u  = (const float*)d_in[4];
    const float* b_u  = (const float*)d_in[5];
    const float* w_hu = (const float*)d_in[6];
    const float* b_hu = (const float*)d_in[7];
    float* g = (float*)d_out;

    float* smax = (float*)d_ws;          // B*T floats
    float* q2c  = smax + B_ * T_;        // B*D floats

    k1_kernel<<<dim3(B_ * NTILE1), dim3(512), 0, stream>>>(h, u, w_h, b_h, w_u, b_u, w_hu, b_hu, g, smax, q2c);
    k3_kernel<<<dim3(B_ * 8), dim3(256), 0, stream>>>(h, smax, q2c);
    k4_kernel<<<dim3(B_ * NTILE1 * 2), dim3(256), 0, stream>>>(h, q2c, g);
}